// Round 8
// baseline (537.154 us; speedup 1.0000x reference)
//
#include <hip/hip_runtime.h>
#include <cstdint>
#include <cstddef>

#define DEVI __device__ __forceinline__

typedef __attribute__((ext_vector_type(8))) short bf16x8;
typedef __attribute__((ext_vector_type(4))) float f32x4;
typedef __attribute__((ext_vector_type(4))) int   i32x4;
typedef unsigned short u16;
typedef unsigned int   u32;

// ---------- helpers ----------
DEVI u16 f2bf(float f) {                      // RNE f32 -> bf16
  u32 u = __float_as_uint(f);
  u += 0x7FFFu + ((u >> 16) & 1u);
  return (u16)(u >> 16);
}

DEVI void gload16(const void* g, void* l) {   // async global->LDS, 16B/lane
  __builtin_amdgcn_global_load_lds((const __attribute__((address_space(1))) u32*)g,
                                   (__attribute__((address_space(3))) u32*)l, 16, 0, 0);
}

DEVI f32x4 MFMA_BF16(bf16x8 a, bf16x8 b, f32x4 c) {
  return __builtin_amdgcn_mfma_f32_16x16x32_bf16(a, b, c, 0, 0, 0);
}
DEVI i32x4 MFMA_I8(i32x4 a, i32x4 b, i32x4 c) {
  return __builtin_amdgcn_mfma_i32_16x16x64_i8(a, b, c, 0, 0, 0);
}

DEVI float slot_scale(const u32* s) {         // scale = max(|x|)/127, eps floor
  return fmaxf(__uint_as_float(*s) * (1.f / 127.f), 1e-8f);
}

DEVI float fexp2(float x) { return __builtin_amdgcn_exp2f(x); }

// ---------- fused init: absmax x5 (z=0..4) + RoPE table (z=5) ----------
__global__ void k_init(const float* __restrict__ hs, const float* __restrict__ wq,
                       const float* __restrict__ wk, const float* __restrict__ wv,
                       const float* __restrict__ wo, float* __restrict__ ct,
                       float* __restrict__ st_, u32* __restrict__ scales) {
  int z = blockIdx.z;
  int tid0 = blockIdx.x * blockDim.x + threadIdx.x;
  int stride = gridDim.x * blockDim.x;
  if (z == 5) {  // RoPE cos/sin table, 2048*64 entries
    for (int t = tid0; t < 131072; t += stride) {
      int s = t >> 6, i = t & 63;
      float invf = expf(-(float)i * (9.210340371976184f / 64.f));  // theta=1e4
      float ang = (float)s * invf;
      ct[t] = cosf(ang);
      st_[t] = sinf(ang);
    }
    return;
  }
  const float* x = (z == 0) ? hs : (z == 1) ? wq : (z == 2) ? wk : (z == 3) ? wv : wo;
  int n4 = (z == 0) ? 2097152 : (z == 2 || z == 3) ? 524288 : 1048576;
  const f32x4* x4 = (const f32x4*)x;
  float m = 0.f;
  for (int i = tid0; i < n4; i += stride) {
    f32x4 v = x4[i];
    m = fmaxf(m, fmaxf(fmaxf(fabsf(v.x), fabsf(v.y)), fmaxf(fabsf(v.z), fabsf(v.w))));
  }
#pragma unroll
  for (int d = 1; d < 64; d <<= 1) m = fmaxf(m, __shfl_xor(m, d));
  if ((threadIdx.x & 63) == 0) atomicMax(scales + z, __float_as_uint(m));
}

// ---------- fused quantize x5 ----------
__global__ void k_quant5(const float* __restrict__ hs, const float* __restrict__ wq,
                         const float* __restrict__ wk, const float* __restrict__ wv,
                         const float* __restrict__ wo, char* __restrict__ xq8,
                         char* __restrict__ wqkv8, char* __restrict__ wo8,
                         const u32* __restrict__ scales) {
  int z = blockIdx.z;
  const float* x; char* o; int n4;
  if (z == 0)      { x = hs; o = xq8;                          n4 = 2097152; }
  else if (z == 1) { x = wq; o = wqkv8;                        n4 = 1048576; }
  else if (z == 2) { x = wk; o = wqkv8 + (size_t)2048 * 2048;  n4 = 524288;  }
  else if (z == 3) { x = wv; o = wqkv8 + (size_t)3072 * 2048;  n4 = 524288;  }
  else             { x = wo; o = wo8;                          n4 = 1048576; }
  float inv = 1.f / slot_scale(scales + z);
  int stride = gridDim.x * blockDim.x;
  for (int i = blockIdx.x * blockDim.x + threadIdx.x; i < n4; i += stride) {
    f32x4 v = ((const f32x4*)x)[i];
    int q0 = (int)fminf(fmaxf(rintf(v.x * inv), -128.f), 127.f);
    int q1 = (int)fminf(fmaxf(rintf(v.y * inv), -128.f), 127.f);
    int q2 = (int)fminf(fmaxf(rintf(v.z * inv), -128.f), 127.f);
    int q3 = (int)fminf(fmaxf(rintf(v.w * inv), -128.f), 127.f);
    ((u32*)o)[i] = (u32)(q0 & 255) | ((u32)(q1 & 255) << 8) |
                   ((u32)(q2 & 255) << 16) | ((u32)(q3 & 255) << 24);
  }
}

__global__ void k_quant_i8(const float* __restrict__ x, char* __restrict__ o,
                           int n4, const u32* __restrict__ slot) {
  float inv = 1.f / slot_scale(slot);
  int i = blockIdx.x * blockDim.x + threadIdx.x;
  if (i >= n4) return;
  f32x4 v = ((const f32x4*)x)[i];
  int q0 = (int)fminf(fmaxf(rintf(v.x * inv), -128.f), 127.f);
  int q1 = (int)fminf(fmaxf(rintf(v.y * inv), -128.f), 127.f);
  int q2 = (int)fminf(fmaxf(rintf(v.z * inv), -128.f), 127.f);
  int q3 = (int)fminf(fmaxf(rintf(v.w * inv), -128.f), 127.f);
  ((u32*)o)[i] = (u32)(q0 & 255) | ((u32)(q1 & 255) << 8) |
                 ((u32)(q2 & 255) << 16) | ((u32)(q3 & 255) << 24);
}

// ---------- int8 GEMM: C[M,N] = (A i8 [M,K]) x (Bt i8 [N,K])^T * (sa*sb) ----------
// 128x128 tile, BK=128, 4 waves, 16x16x64 i8 MFMA, XOR-swizzled LDS (8x16B units/row)
__global__ __launch_bounds__(256) void k_gemm_i8(
    const char* __restrict__ A, const char* __restrict__ Bt, float* __restrict__ C,
    int M, int N, int K, const u32* __restrict__ slots, int slotA, int slotB0, int qkvMode) {
  __shared__ __align__(16) char As[128 * 128];
  __shared__ __align__(16) char Bs[128 * 128];
  // bijective XCD swizzle (nwg % 8 == 0 for both call sites)
  u32 nwg = gridDim.x * gridDim.y;
  u32 bid = blockIdx.y * gridDim.x + blockIdx.x;
  u32 cpx = nwg >> 3;
  u32 swz = (bid & 7) * cpx + (bid >> 3);
  int m0 = (int)(swz / gridDim.x) * 128, n0 = (int)(swz % gridDim.x) * 128;
  int tid = threadIdx.x, lane = tid & 63, w = tid >> 6;
  int wr = w >> 1, wc = w & 1;
  i32x4 acc[4][4] = {};
  int nkt = K >> 7;
  for (int kt = 0; kt < nkt; ++kt) {
    int k0 = kt << 7;
#pragma unroll
    for (int c = 0; c < 4; ++c) {
      int chunk = w * 4 + c;
      int unit = chunk * 64 + lane;
      int r = unit >> 3, p = unit & 7, u = p ^ (r & 7);   // inverse-swizzled source
      gload16(A + (size_t)(m0 + r) * K + k0 + u * 16, ((char*)As) + chunk * 1024);
      gload16(Bt + (size_t)(n0 + r) * K + k0 + u * 16, ((char*)Bs) + chunk * 1024);
    }
    asm volatile("s_waitcnt vmcnt(0)" ::: "memory");
    __syncthreads();
#pragma unroll
    for (int ks = 0; ks < 2; ++ks) {
      i32x4 af[4], bfr[4];
#pragma unroll
      for (int mf = 0; mf < 4; ++mf) {
        int r = wr * 64 + mf * 16 + (lane & 15);
        int u = ks * 4 + (lane >> 4);
        af[mf] = *(const i32x4*)(As + r * 128 + ((u ^ (r & 7)) << 4));
      }
#pragma unroll
      for (int nf = 0; nf < 4; ++nf) {
        int r = wc * 64 + nf * 16 + (lane & 15);
        int u = ks * 4 + (lane >> 4);
        bfr[nf] = *(const i32x4*)(Bs + r * 128 + ((u ^ (r & 7)) << 4));
      }
#pragma unroll
      for (int mf = 0; mf < 4; ++mf)
#pragma unroll
        for (int nf = 0; nf < 4; ++nf)
          acc[mf][nf] = MFMA_I8(af[mf], bfr[nf], acc[mf][nf]);
    }
    __syncthreads();
  }
  float sa = slot_scale(slots + slotA);
  int sbi = slotB0 + (qkvMode ? ((n0 >= 3072) ? 2 : (n0 >= 2048) ? 1 : 0) : 0);
  float ss = sa * slot_scale(slots + sbi);
  int rb = m0 + wr * 64, cb = n0 + wc * 64 + (lane & 15);
#pragma unroll
  for (int mf = 0; mf < 4; ++mf)
#pragma unroll
    for (int nf = 0; nf < 4; ++nf)
#pragma unroll
      for (int j = 0; j < 4; ++j)
        C[(size_t)(rb + mf * 16 + (lane >> 4) * 4 + j) * N + cb + nf * 16] =
            (float)acc[mf][nf][j] * ss;
}

// ---------- RoPE apply + per-head scatter (q and k) ----------
__global__ void k_rope(const float* __restrict__ Y, const float* __restrict__ ct,
                       const float* __restrict__ st_, u16* __restrict__ Qh,
                       u16* __restrict__ Kh) {
  int t = blockIdx.x * blockDim.x + threadIdx.x;
  const int QT = 4096 * 16 * 16;  // q-pairs/4
  bool isq = t < QT;
  int tt = isq ? t : t - QT;
  int d4 = tt & 15;
  int hh = isq ? ((tt >> 4) & 15) : ((tt >> 4) & 7);
  int row = isq ? (tt >> 8) : (tt >> 7);
  int s = row & 2047, bb = row >> 11;
  int d = d4 * 4;
  const float* yp = Y + (size_t)row * 4096 + (isq ? hh * 128 : 2048 + hh * 128) + d;
  f32x4 a = *(const f32x4*)yp;
  f32x4 bv = *(const f32x4*)(yp + 64);
  f32x4 c = *(const f32x4*)(ct + s * 64 + d);
  f32x4 sn = *(const f32x4*)(st_ + s * 64 + d);
  f32x4 o0 = a * c - bv * sn;
  f32x4 o1 = bv * c + a * sn;
  u16* dst = isq ? (Qh + ((size_t)(bb * 16 + hh) * 2048 + s) * 128 + d)
                 : (Kh + ((size_t)(bb * 8 + hh) * 2048 + s) * 128 + d);
  *(uint2*)dst = make_uint2((u32)f2bf(o0.x) | ((u32)f2bf(o0.y) << 16),
                            (u32)f2bf(o0.z) | ((u32)f2bf(o0.w) << 16));
  *(uint2*)(dst + 64) = make_uint2((u32)f2bf(o1.x) | ((u32)f2bf(o1.y) << 16),
                                   (u32)f2bf(o1.z) | ((u32)f2bf(o1.w) << 16));
}

// ---------- V transpose: Y v-cols -> Vth [b][hk][d=128][s=2048] bf16 ----------
__global__ void k_vtrans(const float* __restrict__ Y, u16* __restrict__ Vth) {
  __shared__ u16 tile[64][72];
  int stile = blockIdx.x, dt = blockIdx.y, bh = blockIdx.z;
  int bb = bh >> 3, hk = bh & 7;
  int t = threadIdx.x;
#pragma unroll 4
  for (int i = 0; i < 16; ++i) {
    int e = i * 256 + t;
    int sl = e >> 6, dl = e & 63;
    float v = Y[(size_t)(bb * 2048 + stile * 64 + sl) * 4096 + 3072 + hk * 128 + dt * 64 + dl];
    tile[sl][dl] = f2bf(v);
  }
  __syncthreads();
#pragma unroll 4
  for (int i = 0; i < 16; ++i) {
    int e = i * 256 + t;
    int dl = e >> 6, sl = e & 63;
    Vth[(size_t)((bb * 8 + hk) * 128 + dt * 64 + dl) * 2048 + stile * 64 + sl] = tile[sl][dl];
  }
}

// ---------- flash causal GQA attention (v4) ----------
// ONE WAVE PER BLOCK (64 threads), 32 q-rows/wave, KVBLK=64. No barriers, no
// K/V LDS: K and V fragments read directly from global (L2-resident; XCD-local
// via bid%8==hk mapping). Per-wave private LDS only for the P^T transpose.
// S^T = mfma(K,Q): lane holds scores for q=(lane&15), kv=f*16+(lane>>4)*4+j.
__global__ __launch_bounds__(64) void k_attn(
    const u16* __restrict__ Qh, const u16* __restrict__ Kh, const u16* __restrict__ Vth,
    float* __restrict__ attn, u32* __restrict__ amax_slot) {
  __shared__ __align__(16) u16 Pt[32 * 72];     // [q][kv] bf16, 144 B row stride
  int bid = blockIdx.x;                          // 2048 blocks
  int g = bid & 15, b = g >> 3, hk = g & 7;      // bid%8==hk => same-XCD L2 locality
  int r = bid >> 4, h = hk * 2 + (r & 1), qc = r >> 1;   // qc in [0,64)
  int lane = threadIdx.x & 63, q15 = lane & 15, g4 = lane >> 4;
  const u16* Qbase = Qh + ((size_t)(b * 16 + h) * 2048) * 128;
  const u16* Kbase = Kh + ((size_t)(b * 8 + hk) * 2048) * 128;
  const u16* Vbase = Vth + ((size_t)(b * 8 + hk) * 128) * 2048;
  int qrow0 = qc * 32;
  int qg0 = qrow0 + q15, qg1 = qrow0 + 16 + q15;
  bf16x8 qf0[4], qf1[4];
#pragma unroll
  for (int ks = 0; ks < 4; ++ks) {
    qf0[ks] = *(const bf16x8*)(Qbase + (size_t)qg0 * 128 + ks * 32 + g4 * 8);
    qf1[ks] = *(const bf16x8*)(Qbase + (size_t)qg1 * 128 + ks * 32 + g4 * 8);
  }
  f32x4 o0[8] = {}, o1[8] = {};
  float m0 = -1e30f, m1 = -1e30f, l0 = 0.f, l1 = 0.f;
  const float C2 = 1.4426950408889634f * 0.08838834764831845f;  // log2e/sqrt(128)
  int nkv = (qc >> 1) + 1;
  for (int t = 0; t < nkv; ++t) {
    int kvb = t * 64;
    // ---- K fragments direct from global (compiler inserts vmcnt waits) ----
    bf16x8 kf[4][4];
#pragma unroll
    for (int ks = 0; ks < 4; ++ks)
#pragma unroll
      for (int f = 0; f < 4; ++f)
        kf[ks][f] = *(const bf16x8*)(Kbase + (size_t)(kvb + f * 16 + q15) * 128 +
                                     ks * 32 + g4 * 8);
    // ---- S^T = K x Q^T ----
    f32x4 s0[4] = {}, s1[4] = {};
#pragma unroll
    for (int ks = 0; ks < 4; ++ks)
#pragma unroll
      for (int f = 0; f < 4; ++f) {
        s0[f] = MFMA_BF16(kf[ks][f], qf0[ks], s0[f]);
        s1[f] = MFMA_BF16(kf[ks][f], qf1[ks], s1[f]);
      }
    // ---- scale (+mask on diagonal tile) + tile max ----
    bool needMask = (kvb + 63 > qrow0);
    float t0 = -1e30f, t1 = -1e30f;
#pragma unroll
    for (int f = 0; f < 4; ++f)
#pragma unroll
      for (int j = 0; j < 4; ++j) {
        float x0 = s0[f][j] * C2, x1 = s1[f][j] * C2;
        if (needMask) {
          int kvg = kvb + f * 16 + g4 * 4 + j;
          if (kvg > qg0) x0 = -1e30f;
          if (kvg > qg1) x1 = -1e30f;
        }
        s0[f][j] = x0; s1[f][j] = x1;
        t0 = fmaxf(t0, x0); t1 = fmaxf(t1, x1);
      }
    t0 = fmaxf(t0, __shfl_xor(t0, 16)); t0 = fmaxf(t0, __shfl_xor(t0, 32));
    t1 = fmaxf(t1, __shfl_xor(t1, 16)); t1 = fmaxf(t1, __shfl_xor(t1, 32));
    // ---- defer-max: rescale only when max grew by > 8 (log2) ----
    bool nochg = (t0 <= m0 + 8.f) && (t1 <= m1 + 8.f);
    if (!__all(nochg)) {
      float mn0 = fmaxf(m0, t0), mn1 = fmaxf(m1, t1);
      float a0 = fexp2(m0 - mn0), a1 = fexp2(m1 - mn1);
      m0 = mn0; m1 = mn1;
      l0 *= a0; l1 *= a1;
      float al0[4], al1[4];
#pragma unroll
      for (int j = 0; j < 4; ++j) {
        al0[j] = __shfl(a0, g4 * 4 + j);
        al1[j] = __shfl(a1, g4 * 4 + j);
      }
#pragma unroll
      for (int nf = 0; nf < 8; ++nf)
#pragma unroll
        for (int j = 0; j < 4; ++j) {
          o0[nf][j] *= al0[j];
          o1[nf][j] *= al1[j];
        }
    }
    // ---- P = exp2(s - m), row sums ----
    float ts0 = 0.f, ts1 = 0.f;
#pragma unroll
    for (int f = 0; f < 4; ++f)
#pragma unroll
      for (int j = 0; j < 4; ++j) {
        float p0 = fexp2(s0[f][j] - m0), p1 = fexp2(s1[f][j] - m1);
        s0[f][j] = p0; s1[f][j] = p1;
        ts0 += p0; ts1 += p1;
      }
    ts0 += __shfl_xor(ts0, 16); ts0 += __shfl_xor(ts0, 32);
    ts1 += __shfl_xor(ts1, 16); ts1 += __shfl_xor(ts1, 32);
    l0 += ts0; l1 += ts1;
    // ---- pack P^T to per-wave LDS (bf16); same-wave, no barrier ----
#pragma unroll
    for (int f = 0; f < 4; ++f) {
      *(uint2*)((char*)Pt + q15 * 144 + (f * 16 + g4 * 4) * 2) =
          make_uint2((u32)f2bf(s0[f][0]) | ((u32)f2bf(s0[f][1]) << 16),
                     (u32)f2bf(s0[f][2]) | ((u32)f2bf(s0[f][3]) << 16));
      *(uint2*)((char*)Pt + (16 + q15) * 144 + (f * 16 + g4 * 4) * 2) =
          make_uint2((u32)f2bf(s1[f][0]) | ((u32)f2bf(s1[f][1]) << 16),
                     (u32)f2bf(s1[f][2]) | ((u32)f2bf(s1[f][3]) << 16));
    }
    // ---- PV: O[q][d] += P[q][kv] * V[kv][d]; V direct from global ----
#pragma unroll
    for (int ks2 = 0; ks2 < 2; ++ks2) {
      bf16x8 pf0 = *(const bf16x8*)((char*)Pt + q15 * 144 + (ks2 * 32 + g4 * 8) * 2);
      bf16x8 pf1 = *(const bf16x8*)((char*)Pt + (16 + q15) * 144 + (ks2 * 32 + g4 * 8) * 2);
#pragma unroll
      for (int nf = 0; nf < 8; ++nf) {
        bf16x8 vf = *(const bf16x8*)(Vbase + (size_t)(nf * 16 + q15) * 2048 +
                                     kvb + ks2 * 32 + g4 * 8);
        o0[nf] = MFMA_BF16(pf0, vf, o0[nf]);
        o1[nf] = MFMA_BF16(pf1, vf, o1[nf]);
      }
    }
  }
  // ---- epilogue: normalize, store, fused absmax ----
  float i0 = 1.f / l0, i1 = 1.f / l1;
  float iv0[4], iv1[4];
#pragma unroll
  for (int j = 0; j < 4; ++j) {
    iv0[j] = __shfl(i0, g4 * 4 + j);
    iv1[j] = __shfl(i1, g4 * 4 + j);
  }
  float am = 0.f;
  int colb = h * 128 + q15;
#pragma unroll
  for (int nf = 0; nf < 8; ++nf)
#pragma unroll
    for (int j = 0; j < 4; ++j) {
      int r0 = qrow0 + g4 * 4 + j, r1 = qrow0 + 16 + g4 * 4 + j;
      float v0 = o0[nf][j] * iv0[j], v1 = o1[nf][j] * iv1[j];
      am = fmaxf(am, fmaxf(fabsf(v0), fabsf(v1)));
      attn[(size_t)(b * 2048 + r0) * 2048 + colb + nf * 16] = v0;
      attn[(size_t)(b * 2048 + r1) * 2048 + colb + nf * 16] = v1;
    }
#pragma unroll
  for (int d = 1; d < 64; d <<= 1) am = fmaxf(am, __shfl_xor(am, d));
  if (lane == 0) atomicMax(amax_slot, __float_as_uint(am));
}

// ---------- launch ----------
extern "C" void kernel_launch(void* const* d_in, const int* in_sizes, int n_in,
                              void* d_out, int out_size, void* d_ws, size_t ws_size,
                              hipStream_t stream) {
  const float* hs = (const float*)d_in[0];
  const float* wq = (const float*)d_in[1];
  const float* wk = (const float*)d_in[2];
  const float* wv = (const float*)d_in[3];
  const float* wo = (const float*)d_in[4];
  float* out = (float*)d_out;

  char* ws = (char*)d_ws;
  size_t off = 0;
  u32* scales = (u32*)ws; off += 256;                       // [x,wq,wk,wv,wo,attn]
  char* xq8 = ws + off;   off += (size_t)4096 * 2048;
  char* wqkv8 = ws + off; off += (size_t)4096 * 2048;       // rows: wq|wk|wv
  char* wo8 = ws + off;   off += (size_t)2048 * 2048;
  float* Y = (float*)(ws + off);   off += (size_t)4096 * 4096 * 4;
  u16* Qh = (u16*)(ws + off);      off += (size_t)2 * 16 * 2048 * 128 * 2;
  u16* Kh = (u16*)(ws + off);      off += (size_t)2 * 8 * 2048 * 128 * 2;
  u16* Vth = (u16*)(ws + off);     off += (size_t)2 * 8 * 2048 * 128 * 2;
  float* attnb = (float*)(ws + off); off += (size_t)4096 * 2048 * 4;
  char* attn8 = ws + off;          off += (size_t)4096 * 2048;
  float* ctab = (float*)(ws + off); off += (size_t)2048 * 64 * 4;
  float* stab = (float*)(ws + off); off += (size_t)2048 * 64 * 4;

  hipMemsetAsync(scales, 0, 64, stream);

  hipLaunchKernelGGL(k_init, dim3(256, 1, 6), dim3(256), 0, stream,
                     hs, wq, wk, wv, wo, ctab, stab, scales);
  hipLaunchKernelGGL(k_quant5, dim3(512, 1, 5), dim3(256), 0, stream,
                     hs, wq, wk, wv, wo, xq8, wqkv8, wo8, scales);

  // QKV projection (exact int8): Y[4096][4096] = xq8 * wqkv8^T * scales
  hipLaunchKernelGGL(k_gemm_i8, dim3(32, 32), dim3(256), 0, stream,
                     xq8, wqkv8, Y, 4096, 4096, 2048, scales, 0, 1, 1);

  hipLaunchKernelGGL(k_rope, dim3(6144), dim3(256), 0, stream, Y, ctab, stab, Qh, Kh);
  hipLaunchKernelGGL(k_vtrans, dim3(32, 2, 16), dim3(256), 0, stream, Y, Vth);

  hipLaunchKernelGGL(k_attn, dim3(2048), dim3(64), 0, stream, Qh, Kh, Vth,
                     attnb, scales + 5);

  hipLaunchKernelGGL(k_quant_i8, dim3(8192), dim3(256), 0, stream, attnb, attn8,
                     2097152, scales + 5);

  // output projection (exact int8) -> d_out
  hipLaunchKernelGGL(k_gemm_i8, dim3(16, 32), dim3(256), 0, stream,
                     attn8, wo8, out, 4096, 2048, 2048, scales, 5, 4, 0);
}

// Round 9
// 410.607 us; speedup vs baseline: 1.3082x; 1.3082x over previous
//
#include <hip/hip_runtime.h>
#include <cstdint>
#include <cstddef>

#define DEVI __device__ __forceinline__

typedef __attribute__((ext_vector_type(8))) short bf16x8;
typedef __attribute__((ext_vector_type(4))) float f32x4;
typedef __attribute__((ext_vector_type(4))) int   i32x4;
typedef unsigned short u16;
typedef unsigned int   u32;

// ---------- helpers ----------
DEVI u16 f2bf(float f) {                      // RNE f32 -> bf16
  u32 u = __float_as_uint(f);
  u += 0x7FFFu + ((u >> 16) & 1u);
  return (u16)(u >> 16);
}

DEVI void gload16(const void* g, void* l) {   // async global->LDS, 16B/lane
  __builtin_amdgcn_global_load_lds((const __attribute__((address_space(1))) u32*)g,
                                   (__attribute__((address_space(3))) u32*)l, 16, 0, 0);
}

DEVI f32x4 MFMA_BF16(bf16x8 a, bf16x8 b, f32x4 c) {
  return __builtin_amdgcn_mfma_f32_16x16x32_bf16(a, b, c, 0, 0, 0);
}
DEVI i32x4 MFMA_I8(i32x4 a, i32x4 b, i32x4 c) {
  return __builtin_amdgcn_mfma_i32_16x16x64_i8(a, b, c, 0, 0, 0);
}

DEVI float slot_scale(const u32* s) {         // scale = max(|x|)/127, eps floor
  return fmaxf(__uint_as_float(*s) * (1.f / 127.f), 1e-8f);
}

DEVI float fexp2(float x) { return __builtin_amdgcn_exp2f(x); }

// ---------- fused init: absmax x5 (z=0..4) + RoPE table (z=5) ----------
__global__ void k_init(const float* __restrict__ hs, const float* __restrict__ wq,
                       const float* __restrict__ wk, const float* __restrict__ wv,
                       const float* __restrict__ wo, float* __restrict__ ct,
                       float* __restrict__ st_, u32* __restrict__ scales) {
  int z = blockIdx.z;
  int tid0 = blockIdx.x * blockDim.x + threadIdx.x;
  int stride = gridDim.x * blockDim.x;
  if (z == 5) {  // RoPE cos/sin table, 2048*64 entries
    for (int t = tid0; t < 131072; t += stride) {
      int s = t >> 6, i = t & 63;
      float invf = expf(-(float)i * (9.210340371976184f / 64.f));  // theta=1e4
      float ang = (float)s * invf;
      ct[t] = cosf(ang);
      st_[t] = sinf(ang);
    }
    return;
  }
  const float* x = (z == 0) ? hs : (z == 1) ? wq : (z == 2) ? wk : (z == 3) ? wv : wo;
  int n4 = (z == 0) ? 2097152 : (z == 2 || z == 3) ? 524288 : 1048576;
  const f32x4* x4 = (const f32x4*)x;
  float m = 0.f;
  for (int i = tid0; i < n4; i += stride) {
    f32x4 v = x4[i];
    m = fmaxf(m, fmaxf(fmaxf(fabsf(v.x), fabsf(v.y)), fmaxf(fabsf(v.z), fabsf(v.w))));
  }
#pragma unroll
  for (int d = 1; d < 64; d <<= 1) m = fmaxf(m, __shfl_xor(m, d));
  if ((threadIdx.x & 63) == 0) atomicMax(scales + z, __float_as_uint(m));
}

// ---------- fused quantize x5 ----------
__global__ void k_quant5(const float* __restrict__ hs, const float* __restrict__ wq,
                         const float* __restrict__ wk, const float* __restrict__ wv,
                         const float* __restrict__ wo, char* __restrict__ xq8,
                         char* __restrict__ wqkv8, char* __restrict__ wo8,
                         const u32* __restrict__ scales) {
  int z = blockIdx.z;
  const float* x; char* o; int n4;
  if (z == 0)      { x = hs; o = xq8;                          n4 = 2097152; }
  else if (z == 1) { x = wq; o = wqkv8;                        n4 = 1048576; }
  else if (z == 2) { x = wk; o = wqkv8 + (size_t)2048 * 2048;  n4 = 524288;  }
  else if (z == 3) { x = wv; o = wqkv8 + (size_t)3072 * 2048;  n4 = 524288;  }
  else             { x = wo; o = wo8;                          n4 = 1048576; }
  float inv = 1.f / slot_scale(scales + z);
  int stride = gridDim.x * blockDim.x;
  for (int i = blockIdx.x * blockDim.x + threadIdx.x; i < n4; i += stride) {
    f32x4 v = ((const f32x4*)x)[i];
    int q0 = (int)fminf(fmaxf(rintf(v.x * inv), -128.f), 127.f);
    int q1 = (int)fminf(fmaxf(rintf(v.y * inv), -128.f), 127.f);
    int q2 = (int)fminf(fmaxf(rintf(v.z * inv), -128.f), 127.f);
    int q3 = (int)fminf(fmaxf(rintf(v.w * inv), -128.f), 127.f);
    ((u32*)o)[i] = (u32)(q0 & 255) | ((u32)(q1 & 255) << 8) |
                   ((u32)(q2 & 255) << 16) | ((u32)(q3 & 255) << 24);
  }
}

__global__ void k_quant_i8(const float* __restrict__ x, char* __restrict__ o,
                           int n4, const u32* __restrict__ slot) {
  float inv = 1.f / slot_scale(slot);
  int i = blockIdx.x * blockDim.x + threadIdx.x;
  if (i >= n4) return;
  f32x4 v = ((const f32x4*)x)[i];
  int q0 = (int)fminf(fmaxf(rintf(v.x * inv), -128.f), 127.f);
  int q1 = (int)fminf(fmaxf(rintf(v.y * inv), -128.f), 127.f);
  int q2 = (int)fminf(fmaxf(rintf(v.z * inv), -128.f), 127.f);
  int q3 = (int)fminf(fmaxf(rintf(v.w * inv), -128.f), 127.f);
  ((u32*)o)[i] = (u32)(q0 & 255) | ((u32)(q1 & 255) << 8) |
                 ((u32)(q2 & 255) << 16) | ((u32)(q3 & 255) << 24);
}

// ---------- int8 GEMM: C[M,N] = (A i8 [M,K]) x (Bt i8 [N,K])^T * (sa*sb) ----------
// 128x128 tile, BK=128, 4 waves, 16x16x64 i8 MFMA, XOR-swizzled LDS (8x16B units/row)
__global__ __launch_bounds__(256) void k_gemm_i8(
    const char* __restrict__ A, const char* __restrict__ Bt, float* __restrict__ C,
    int M, int N, int K, const u32* __restrict__ slots, int slotA, int slotB0, int qkvMode) {
  __shared__ __align__(16) char As[128 * 128];
  __shared__ __align__(16) char Bs[128 * 128];
  // bijective XCD swizzle (nwg % 8 == 0 for both call sites)
  u32 nwg = gridDim.x * gridDim.y;
  u32 bid = blockIdx.y * gridDim.x + blockIdx.x;
  u32 cpx = nwg >> 3;
  u32 swz = (bid & 7) * cpx + (bid >> 3);
  int m0 = (int)(swz / gridDim.x) * 128, n0 = (int)(swz % gridDim.x) * 128;
  int tid = threadIdx.x, lane = tid & 63, w = tid >> 6;
  int wr = w >> 1, wc = w & 1;
  i32x4 acc[4][4] = {};
  int nkt = K >> 7;
  for (int kt = 0; kt < nkt; ++kt) {
    int k0 = kt << 7;
#pragma unroll
    for (int c = 0; c < 4; ++c) {
      int chunk = w * 4 + c;
      int unit = chunk * 64 + lane;
      int r = unit >> 3, p = unit & 7, u = p ^ (r & 7);   // inverse-swizzled source
      gload16(A + (size_t)(m0 + r) * K + k0 + u * 16, ((char*)As) + chunk * 1024);
      gload16(Bt + (size_t)(n0 + r) * K + k0 + u * 16, ((char*)Bs) + chunk * 1024);
    }
    asm volatile("s_waitcnt vmcnt(0)" ::: "memory");
    __syncthreads();
#pragma unroll
    for (int ks = 0; ks < 2; ++ks) {
      i32x4 af[4], bfr[4];
#pragma unroll
      for (int mf = 0; mf < 4; ++mf) {
        int r = wr * 64 + mf * 16 + (lane & 15);
        int u = ks * 4 + (lane >> 4);
        af[mf] = *(const i32x4*)(As + r * 128 + ((u ^ (r & 7)) << 4));
      }
#pragma unroll
      for (int nf = 0; nf < 4; ++nf) {
        int r = wc * 64 + nf * 16 + (lane & 15);
        int u = ks * 4 + (lane >> 4);
        bfr[nf] = *(const i32x4*)(Bs + r * 128 + ((u ^ (r & 7)) << 4));
      }
#pragma unroll
      for (int mf = 0; mf < 4; ++mf)
#pragma unroll
        for (int nf = 0; nf < 4; ++nf)
          acc[mf][nf] = MFMA_I8(af[mf], bfr[nf], acc[mf][nf]);
    }
    __syncthreads();
  }
  float sa = slot_scale(slots + slotA);
  int sbi = slotB0 + (qkvMode ? ((n0 >= 3072) ? 2 : (n0 >= 2048) ? 1 : 0) : 0);
  float ss = sa * slot_scale(slots + sbi);
  int rb = m0 + wr * 64, cb = n0 + wc * 64 + (lane & 15);
#pragma unroll
  for (int mf = 0; mf < 4; ++mf)
#pragma unroll
    for (int nf = 0; nf < 4; ++nf)
#pragma unroll
      for (int j = 0; j < 4; ++j)
        C[(size_t)(rb + mf * 16 + (lane >> 4) * 4 + j) * N + cb + nf * 16] =
            (float)acc[mf][nf][j] * ss;
}

// ---------- RoPE apply + per-head scatter (q and k) ----------
__global__ void k_rope(const float* __restrict__ Y, const float* __restrict__ ct,
                       const float* __restrict__ st_, u16* __restrict__ Qh,
                       u16* __restrict__ Kh) {
  int t = blockIdx.x * blockDim.x + threadIdx.x;
  const int QT = 4096 * 16 * 16;  // q-pairs/4
  bool isq = t < QT;
  int tt = isq ? t : t - QT;
  int d4 = tt & 15;
  int hh = isq ? ((tt >> 4) & 15) : ((tt >> 4) & 7);
  int row = isq ? (tt >> 8) : (tt >> 7);
  int s = row & 2047, bb = row >> 11;
  int d = d4 * 4;
  const float* yp = Y + (size_t)row * 4096 + (isq ? hh * 128 : 2048 + hh * 128) + d;
  f32x4 a = *(const f32x4*)yp;
  f32x4 bv = *(const f32x4*)(yp + 64);
  f32x4 c = *(const f32x4*)(ct + s * 64 + d);
  f32x4 sn = *(const f32x4*)(st_ + s * 64 + d);
  f32x4 o0 = a * c - bv * sn;
  f32x4 o1 = bv * c + a * sn;
  u16* dst = isq ? (Qh + ((size_t)(bb * 16 + hh) * 2048 + s) * 128 + d)
                 : (Kh + ((size_t)(bb * 8 + hh) * 2048 + s) * 128 + d);
  *(uint2*)dst = make_uint2((u32)f2bf(o0.x) | ((u32)f2bf(o0.y) << 16),
                            (u32)f2bf(o0.z) | ((u32)f2bf(o0.w) << 16));
  *(uint2*)(dst + 64) = make_uint2((u32)f2bf(o1.x) | ((u32)f2bf(o1.y) << 16),
                                   (u32)f2bf(o1.z) | ((u32)f2bf(o1.w) << 16));
}

// ---------- V transpose: Y v-cols -> Vth [b][hk][d=128][s=2048] bf16 ----------
__global__ void k_vtrans(const float* __restrict__ Y, u16* __restrict__ Vth) {
  __shared__ u16 tile[64][72];
  int stile = blockIdx.x, dt = blockIdx.y, bh = blockIdx.z;
  int bb = bh >> 3, hk = bh & 7;
  int t = threadIdx.x;
#pragma unroll 4
  for (int i = 0; i < 16; ++i) {
    int e = i * 256 + t;
    int sl = e >> 6, dl = e & 63;
    float v = Y[(size_t)(bb * 2048 + stile * 64 + sl) * 4096 + 3072 + hk * 128 + dt * 64 + dl];
    tile[sl][dl] = f2bf(v);
  }
  __syncthreads();
#pragma unroll 4
  for (int i = 0; i < 16; ++i) {
    int e = i * 256 + t;
    int dl = e >> 6, sl = e & 63;
    Vth[(size_t)((bb * 8 + hk) * 128 + dt * 64 + dl) * 2048 + stile * 64 + sl] = tile[sl][dl];
  }
}

// ---------- flash causal GQA attention (v5) ----------
// 4 waves x 32 q-rows = QBLK 128; KVBLK=64. Deterministic qt-pairing: block p
// processes q-tiles {p, 15-p} sequentially => uniform 34 kv-iterations/block,
// 256 blocks (1/CU, no tail). K double-buffered via global_load_lds; V staged
// via registers (issue at top of iter, ds_write after compute) so HBM/L2
// latency hides under QK^T+softmax+PV. Plain __syncthreads (drains are
// harmless: in-flight data is next-iter's, needed at the barrier anyway).
__global__ __launch_bounds__(256, 2) void k_attn(
    const u16* __restrict__ Qh, const u16* __restrict__ Kh, const u16* __restrict__ Vth,
    float* __restrict__ attn, u32* __restrict__ amax_slot) {
  __shared__ __align__(16) u16 Ks[2][64 * 128];  // [kv][d], 16 units/row, XOR-swizzled
  __shared__ __align__(16) u16 Vts[128 * 64];    // [d][kv], 8 units/row, XOR-swizzled
  __shared__ __align__(16) u16 Pt[128 * 72];     // [q][kv], 144 B row stride
  int bid = blockIdx.x;                          // 256 blocks
  int hk = bid & 7, b = (bid >> 3) & 1;          // bid%8==hk => XCD-local K/V
  int r = bid >> 4, hpar = r & 1, p = r >> 1;    // p in [0,8)
  int h = hk * 2 + hpar;
  int tid = threadIdx.x, lane = tid & 63, w = tid >> 6;
  int q15 = lane & 15, g4 = lane >> 4;
  const u16* Qbase = Qh + ((size_t)(b * 16 + h) * 2048) * 128;
  const u16* Kbase = Kh + ((size_t)(b * 8 + hk) * 2048) * 128;
  const u16* Vbase = Vth + ((size_t)(b * 8 + hk) * 128) * 2048;
  const float C2 = 1.4426950408889634f * 0.08838834764831845f;  // log2e/sqrt(128)
  float am = 0.f;

  uint4 vreg[4];
  auto stage_k = [&](int kvb, u16* buf) {
#pragma unroll
    for (int c = 0; c < 4; ++c) {
      int chunk = w * 4 + c;
      int unit = chunk * 64 + lane;
      int rk = unit >> 4, pk = unit & 15, uk = pk ^ (rk & 7);
      gload16(Kbase + (size_t)(kvb + rk) * 128 + uk * 8, ((char*)buf) + chunk * 1024);
    }
  };
  auto load_v = [&](int kvb) {
#pragma unroll
    for (int c = 0; c < 4; ++c) {
      int chunk = w * 4 + c;
      int unit = chunk * 64 + lane;
      int rv = unit >> 3, pv = unit & 7, uv = pv ^ (rv & 7);
      vreg[c] = *(const uint4*)(Vbase + (size_t)rv * 2048 + kvb + uv * 8);
    }
  };
  auto write_v = [&]() {
#pragma unroll
    for (int c = 0; c < 4; ++c)
      *(uint4*)((char*)Vts + (w * 4 + c) * 1024 + lane * 16) = vreg[c];
  };

  for (int sub = 0; sub < 2; ++sub) {
    int qt = sub ? 15 - p : p;
    int qrow0 = qt * 128 + w * 32;
    int qg0 = qrow0 + q15, qg1 = qrow0 + 16 + q15;
    bf16x8 qf0[4], qf1[4];
#pragma unroll
    for (int ks = 0; ks < 4; ++ks) {
      qf0[ks] = *(const bf16x8*)(Qbase + (size_t)qg0 * 128 + ks * 32 + g4 * 8);
      qf1[ks] = *(const bf16x8*)(Qbase + (size_t)qg1 * 128 + ks * 32 + g4 * 8);
    }
    f32x4 o0[8] = {}, o1[8] = {};
    float m0 = -1e30f, m1 = -1e30f, l0 = 0.f, l1 = 0.f;
    int nkv = 2 * qt + 2;
    // prologue: tile 0 into Ks[0]/Vts
    stage_k(0, Ks[0]);
    load_v(0);
    __syncthreads();
    write_v();
    __syncthreads();
    int cur = 0;
    for (int t = 0; t < nkv; ++t) {
      int kvb = t * 64;
      bool more = (t + 1 < nkv);
      if (more) {
        stage_k(kvb + 64, Ks[cur ^ 1]);  // async into alternate buffer
        load_v(kvb + 64);                // V(t+1) into regs; latency hides under compute
      }
      bool active = (kvb <= qrow0 + 31);
      if (active) {
        const char* Kb = (const char*)Ks[cur];
        // ---- S^T = K x Q^T ----
        f32x4 s0[4] = {}, s1[4] = {};
#pragma unroll
        for (int ks = 0; ks < 4; ++ks)
#pragma unroll
          for (int f = 0; f < 4; ++f) {
            int rr = f * 16 + q15;
            int u = ks * 4 + g4;
            bf16x8 kf = *(const bf16x8*)(Kb + rr * 256 + ((u ^ (rr & 7)) << 4));
            s0[f] = MFMA_BF16(kf, qf0[ks], s0[f]);
            s1[f] = MFMA_BF16(kf, qf1[ks], s1[f]);
          }
        // ---- scale (+mask on diagonal tile) + tile max ----
        bool needMask = (kvb + 63 > qrow0);
        float t0 = -1e30f, t1 = -1e30f;
#pragma unroll
        for (int f = 0; f < 4; ++f)
#pragma unroll
          for (int j = 0; j < 4; ++j) {
            float x0 = s0[f][j] * C2, x1 = s1[f][j] * C2;
            if (needMask) {
              int kvg = kvb + f * 16 + g4 * 4 + j;
              if (kvg > qg0) x0 = -1e30f;
              if (kvg > qg1) x1 = -1e30f;
            }
            s0[f][j] = x0; s1[f][j] = x1;
            t0 = fmaxf(t0, x0); t1 = fmaxf(t1, x1);
          }
        t0 = fmaxf(t0, __shfl_xor(t0, 16)); t0 = fmaxf(t0, __shfl_xor(t0, 32));
        t1 = fmaxf(t1, __shfl_xor(t1, 16)); t1 = fmaxf(t1, __shfl_xor(t1, 32));
        // ---- defer-max ----
        bool nochg = (t0 <= m0 + 8.f) && (t1 <= m1 + 8.f);
        if (!__all(nochg)) {
          float mn0 = fmaxf(m0, t0), mn1 = fmaxf(m1, t1);
          float a0 = fexp2(m0 - mn0), a1 = fexp2(m1 - mn1);
          m0 = mn0; m1 = mn1;
          l0 *= a0; l1 *= a1;
          float al0[4], al1[4];
#pragma unroll
          for (int j = 0; j < 4; ++j) {
            al0[j] = __shfl(a0, g4 * 4 + j);
            al1[j] = __shfl(a1, g4 * 4 + j);
          }
#pragma unroll
          for (int nf = 0; nf < 8; ++nf)
#pragma unroll
            for (int j = 0; j < 4; ++j) {
              o0[nf][j] *= al0[j];
              o1[nf][j] *= al1[j];
            }
        }
        // ---- P = exp2(s - m), row sums ----
        float ts0 = 0.f, ts1 = 0.f;
#pragma unroll
        for (int f = 0; f < 4; ++f)
#pragma unroll
          for (int j = 0; j < 4; ++j) {
            float p0 = fexp2(s0[f][j] - m0), p1 = fexp2(s1[f][j] - m1);
            s0[f][j] = p0; s1[f][j] = p1;
            ts0 += p0; ts1 += p1;
          }
        ts0 += __shfl_xor(ts0, 16); ts0 += __shfl_xor(ts0, 32);
        ts1 += __shfl_xor(ts1, 16); ts1 += __shfl_xor(ts1, 32);
        l0 += ts0; l1 += ts1;
        // ---- pack P^T to LDS (wave-private rows, no barrier needed) ----
#pragma unroll
        for (int f = 0; f < 4; ++f) {
          *(uint2*)((char*)Pt + (w * 32 + q15) * 144 + (f * 16 + g4 * 4) * 2) =
              make_uint2((u32)f2bf(s0[f][0]) | ((u32)f2bf(s0[f][1]) << 16),
                         (u32)f2bf(s0[f][2]) | ((u32)f2bf(s0[f][3]) << 16));
          *(uint2*)((char*)Pt + (w * 32 + 16 + q15) * 144 + (f * 16 + g4 * 4) * 2) =
              make_uint2((u32)f2bf(s1[f][0]) | ((u32)f2bf(s1[f][1]) << 16),
                         (u32)f2bf(s1[f][2]) | ((u32)f2bf(s1[f][3]) << 16));
        }
        // ---- PV ----
#pragma unroll
        for (int ks2 = 0; ks2 < 2; ++ks2) {
          bf16x8 pf0 = *(const bf16x8*)((char*)Pt + (w * 32 + q15) * 144 +
                                        (ks2 * 32 + g4 * 8) * 2);
          bf16x8 pf1 = *(const bf16x8*)((char*)Pt + (w * 32 + 16 + q15) * 144 +
                                        (ks2 * 32 + g4 * 8) * 2);
#pragma unroll
          for (int nf = 0; nf < 8; ++nf) {
            int rv = nf * 16 + q15;
            int u = ks2 * 4 + g4;
            bf16x8 vf = *(const bf16x8*)((const char*)Vts + rv * 128 + ((u ^ (rv & 7)) << 4));
            o0[nf] = MFMA_BF16(pf0, vf, o0[nf]);
            o1[nf] = MFMA_BF16(pf1, vf, o1[nf]);
          }
        }
      }
      __syncthreads();            // all PV reads of Vts done (+ drains K/V in flight)
      if (more) write_v();        // V(t+1) -> Vts
      __syncthreads();            // Vts(t+1) visible; Ks[cur^1] resident
      cur ^= 1;
    }
    // ---- epilogue: normalize, store, absmax accumulate ----
    float i0 = 1.f / l0, i1 = 1.f / l1;
    float iv0[4], iv1[4];
#pragma unroll
    for (int j = 0; j < 4; ++j) {
      iv0[j] = __shfl(i0, g4 * 4 + j);
      iv1[j] = __shfl(i1, g4 * 4 + j);
    }
    int colb = h * 128 + q15;
#pragma unroll
    for (int nf = 0; nf < 8; ++nf)
#pragma unroll
      for (int j = 0; j < 4; ++j) {
        int r0 = qrow0 + g4 * 4 + j, r1 = qrow0 + 16 + g4 * 4 + j;
        float v0 = o0[nf][j] * iv0[j], v1 = o1[nf][j] * iv1[j];
        am = fmaxf(am, fmaxf(fabsf(v0), fabsf(v1)));
        attn[(size_t)(b * 2048 + r0) * 2048 + colb + nf * 16] = v0;
        attn[(size_t)(b * 2048 + r1) * 2048 + colb + nf * 16] = v1;
      }
  }
#pragma unroll
  for (int d = 1; d < 64; d <<= 1) am = fmaxf(am, __shfl_xor(am, d));
  if (lane == 0) atomicMax(amax_slot, __float_as_uint(am));
}

// ---------- launch ----------
extern "C" void kernel_launch(void* const* d_in, const int* in_sizes, int n_in,
                              void* d_out, int out_size, void* d_ws, size_t ws_size,
                              hipStream_t stream) {
  const float* hs = (const float*)d_in[0];
  const float* wq = (const float*)d_in[1];
  const float* wk = (const float*)d_in[2];
  const float* wv = (const float*)d_in[3];
  const float* wo = (const float*)d_in[4];
  float* out = (float*)d_out;

  char* ws = (char*)d_ws;
  size_t off = 0;
  u32* scales = (u32*)ws; off += 256;                       // [x,wq,wk,wv,wo,attn]
  char* xq8 = ws + off;   off += (size_t)4096 * 2048;
  char* wqkv8 = ws + off; off += (size_t)4096 * 2048;       // rows: wq|wk|wv
  char* wo8 = ws + off;   off += (size_t)2048 * 2048;
  float* Y = (float*)(ws + off);   off += (size_t)4096 * 4096 * 4;
  u16* Qh = (u16*)(ws + off);      off += (size_t)2 * 16 * 2048 * 128 * 2;
  u16* Kh = (u16*)(ws + off);      off += (size_t)2 * 8 * 2048 * 128 * 2;
  u16* Vth = (u16*)(ws + off);     off += (size_t)2 * 8 * 2048 * 128 * 2;
  float* attnb = (float*)(ws + off); off += (size_t)4096 * 2048 * 4;
  char* attn8 = ws + off;          off += (size_t)4096 * 2048;
  float* ctab = (float*)(ws + off); off += (size_t)2048 * 64 * 4;
  float* stab = (float*)(ws + off); off += (size_t)2048 * 64 * 4;

  hipMemsetAsync(scales, 0, 64, stream);

  hipLaunchKernelGGL(k_init, dim3(256, 1, 6), dim3(256), 0, stream,
                     hs, wq, wk, wv, wo, ctab, stab, scales);
  hipLaunchKernelGGL(k_quant5, dim3(512, 1, 5), dim3(256), 0, stream,
                     hs, wq, wk, wv, wo, xq8, wqkv8, wo8, scales);

  // QKV projection (exact int8): Y[4096][4096] = xq8 * wqkv8^T * scales
  hipLaunchKernelGGL(k_gemm_i8, dim3(32, 32), dim3(256), 0, stream,
                     xq8, wqkv8, Y, 4096, 4096, 2048, scales, 0, 1, 1);

  hipLaunchKernelGGL(k_rope, dim3(6144), dim3(256), 0, stream, Y, ctab, stab, Qh, Kh);
  hipLaunchKernelGGL(k_vtrans, dim3(32, 2, 16), dim3(256), 0, stream, Y, Vth);

  hipLaunchKernelGGL(k_attn, dim3(256), dim3(256), 0, stream, Qh, Kh, Vth,
                     attnb, scales + 5);

  hipLaunchKernelGGL(k_quant_i8, dim3(8192), dim3(256), 0, stream, attnb, attn8,
                     2097152, scales + 5);

  // output projection (exact int8) -> d_out
  hipLaunchKernelGGL(k_gemm_i8, dim3(16, 32), dim3(256), 0, stream,
                     attn8, wo8, out, 4096, 2048, 2048, scales, 5, 4, 0);
}

// Round 10
// 375.080 us; speedup vs baseline: 1.4321x; 1.0947x over previous
//
#include <hip/hip_runtime.h>
#include <cstdint>
#include <cstddef>

#define DEVI __device__ __forceinline__

typedef __attribute__((ext_vector_type(8))) short bf16x8;
typedef __attribute__((ext_vector_type(4))) float f32x4;
typedef __attribute__((ext_vector_type(4))) int   i32x4;
typedef unsigned short u16;
typedef unsigned int   u32;

// ---------- helpers ----------
DEVI u16 f2bf(float f) {                      // RNE f32 -> bf16
  u32 u = __float_as_uint(f);
  u += 0x7FFFu + ((u >> 16) & 1u);
  return (u16)(u >> 16);
}
DEVI float bf2f(u16 v) { return __uint_as_float((u32)v << 16); }

DEVI u32 cvtpk(float lo, float hi) {          // packed f32x2 -> bf16x2 (1 VALU op)
  u32 r;
  asm("v_cvt_pk_bf16_f32 %0, %1, %2" : "=v"(r) : "v"(lo), "v"(hi));
  return r;
}

DEVI void gload16(const void* g, void* l) {   // async global->LDS, 16B/lane
  __builtin_amdgcn_global_load_lds((const __attribute__((address_space(1))) u32*)g,
                                   (__attribute__((address_space(3))) u32*)l, 16, 0, 0);
}

DEVI f32x4 MFMA_BF16(bf16x8 a, bf16x8 b, f32x4 c) {
  return __builtin_amdgcn_mfma_f32_16x16x32_bf16(a, b, c, 0, 0, 0);
}
DEVI i32x4 MFMA_I8(i32x4 a, i32x4 b, i32x4 c) {
  return __builtin_amdgcn_mfma_i32_16x16x64_i8(a, b, c, 0, 0, 0);
}

DEVI float slot_scale(const u32* s) {         // scale = max(|x|)/127, eps floor
  return fmaxf(__uint_as_float(*s) * (1.f / 127.f), 1e-8f);
}

DEVI float fexp2(float x) { return __builtin_amdgcn_exp2f(x); }

// ---------- fused init: absmax x5 (z=0..4) + RoPE table (z=5) ----------
__global__ void k_init(const float* __restrict__ hs, const float* __restrict__ wq,
                       const float* __restrict__ wk, const float* __restrict__ wv,
                       const float* __restrict__ wo, float* __restrict__ ct,
                       float* __restrict__ st_, u32* __restrict__ scales) {
  int z = blockIdx.z;
  int tid0 = blockIdx.x * blockDim.x + threadIdx.x;
  int stride = gridDim.x * blockDim.x;
  if (z == 5) {  // RoPE cos/sin table, 2048*64 entries
    for (int t = tid0; t < 131072; t += stride) {
      int s = t >> 6, i = t & 63;
      float invf = expf(-(float)i * (9.210340371976184f / 64.f));  // theta=1e4
      float ang = (float)s * invf;
      ct[t] = cosf(ang);
      st_[t] = sinf(ang);
    }
    return;
  }
  const float* x = (z == 0) ? hs : (z == 1) ? wq : (z == 2) ? wk : (z == 3) ? wv : wo;
  int n4 = (z == 0) ? 2097152 : (z == 2 || z == 3) ? 524288 : 1048576;
  const f32x4* x4 = (const f32x4*)x;
  float m = 0.f;
  for (int i = tid0; i < n4; i += stride) {
    f32x4 v = x4[i];
    m = fmaxf(m, fmaxf(fmaxf(fabsf(v.x), fabsf(v.y)), fmaxf(fabsf(v.z), fabsf(v.w))));
  }
#pragma unroll
  for (int d = 1; d < 64; d <<= 1) m = fmaxf(m, __shfl_xor(m, d));
  if ((threadIdx.x & 63) == 0) atomicMax(scales + z, __float_as_uint(m));
}

// ---------- fused quantize x5 ----------
__global__ void k_quant5(const float* __restrict__ hs, const float* __restrict__ wq,
                         const float* __restrict__ wk, const float* __restrict__ wv,
                         const float* __restrict__ wo, char* __restrict__ xq8,
                         char* __restrict__ wqkv8, char* __restrict__ wo8,
                         const u32* __restrict__ scales) {
  int z = blockIdx.z;
  const float* x; char* o; int n4;
  if (z == 0)      { x = hs; o = xq8;                          n4 = 2097152; }
  else if (z == 1) { x = wq; o = wqkv8;                        n4 = 1048576; }
  else if (z == 2) { x = wk; o = wqkv8 + (size_t)2048 * 2048;  n4 = 524288;  }
  else if (z == 3) { x = wv; o = wqkv8 + (size_t)3072 * 2048;  n4 = 524288;  }
  else             { x = wo; o = wo8;                          n4 = 1048576; }
  float inv = 1.f / slot_scale(scales + z);
  int stride = gridDim.x * blockDim.x;
  for (int i = blockIdx.x * blockDim.x + threadIdx.x; i < n4; i += stride) {
    f32x4 v = ((const f32x4*)x)[i];
    int q0 = (int)fminf(fmaxf(rintf(v.x * inv), -128.f), 127.f);
    int q1 = (int)fminf(fmaxf(rintf(v.y * inv), -128.f), 127.f);
    int q2 = (int)fminf(fmaxf(rintf(v.z * inv), -128.f), 127.f);
    int q3 = (int)fminf(fmaxf(rintf(v.w * inv), -128.f), 127.f);
    ((u32*)o)[i] = (u32)(q0 & 255) | ((u32)(q1 & 255) << 8) |
                   ((u32)(q2 & 255) << 16) | ((u32)(q3 & 255) << 24);
  }
}

__global__ void k_quant_i8(const float* __restrict__ x, char* __restrict__ o,
                           int n4, const u32* __restrict__ slot) {
  float inv = 1.f / slot_scale(slot);
  int i = blockIdx.x * blockDim.x + threadIdx.x;
  if (i >= n4) return;
  f32x4 v = ((const f32x4*)x)[i];
  int q0 = (int)fminf(fmaxf(rintf(v.x * inv), -128.f), 127.f);
  int q1 = (int)fminf(fmaxf(rintf(v.y * inv), -128.f), 127.f);
  int q2 = (int)fminf(fmaxf(rintf(v.z * inv), -128.f), 127.f);
  int q3 = (int)fminf(fmaxf(rintf(v.w * inv), -128.f), 127.f);
  ((u32*)o)[i] = (u32)(q0 & 255) | ((u32)(q1 & 255) << 8) |
                 ((u32)(q2 & 255) << 16) | ((u32)(q3 & 255) << 24);
}

// ---------- int8 GEMM: C[M,N] = (A i8 [M,K]) x (Bt i8 [N,K])^T * (sa*sb) ----------
// 128x128 tile, BK=128, 4 waves, 16x16x64 i8 MFMA, XOR-swizzled LDS.
// outBf16: 1 -> write bf16 (QKV path), 0 -> write f32 (O-proj path).
__global__ __launch_bounds__(256) void k_gemm_i8(
    const char* __restrict__ A, const char* __restrict__ Bt, void* __restrict__ Cv,
    int M, int N, int K, const u32* __restrict__ slots, int slotA, int slotB0,
    int qkvMode, int outBf16) {
  __shared__ __align__(16) char As[128 * 128];
  __shared__ __align__(16) char Bs[128 * 128];
  u32 nwg = gridDim.x * gridDim.y;
  u32 bid = blockIdx.y * gridDim.x + blockIdx.x;
  u32 cpx = nwg >> 3;
  u32 swz = (bid & 7) * cpx + (bid >> 3);
  int m0 = (int)(swz / gridDim.x) * 128, n0 = (int)(swz % gridDim.x) * 128;
  int tid = threadIdx.x, lane = tid & 63, w = tid >> 6;
  int wr = w >> 1, wc = w & 1;
  i32x4 acc[4][4] = {};
  int nkt = K >> 7;
  for (int kt = 0; kt < nkt; ++kt) {
    int k0 = kt << 7;
#pragma unroll
    for (int c = 0; c < 4; ++c) {
      int chunk = w * 4 + c;
      int unit = chunk * 64 + lane;
      int r = unit >> 3, p = unit & 7, u = p ^ (r & 7);   // inverse-swizzled source
      gload16(A + (size_t)(m0 + r) * K + k0 + u * 16, ((char*)As) + chunk * 1024);
      gload16(Bt + (size_t)(n0 + r) * K + k0 + u * 16, ((char*)Bs) + chunk * 1024);
    }
    asm volatile("s_waitcnt vmcnt(0)" ::: "memory");
    __syncthreads();
#pragma unroll
    for (int ks = 0; ks < 2; ++ks) {
      i32x4 af[4], bfr[4];
#pragma unroll
      for (int mf = 0; mf < 4; ++mf) {
        int r = wr * 64 + mf * 16 + (lane & 15);
        int u = ks * 4 + (lane >> 4);
        af[mf] = *(const i32x4*)(As + r * 128 + ((u ^ (r & 7)) << 4));
      }
#pragma unroll
      for (int nf = 0; nf < 4; ++nf) {
        int r = wc * 64 + nf * 16 + (lane & 15);
        int u = ks * 4 + (lane >> 4);
        bfr[nf] = *(const i32x4*)(Bs + r * 128 + ((u ^ (r & 7)) << 4));
      }
#pragma unroll
      for (int mf = 0; mf < 4; ++mf)
#pragma unroll
        for (int nf = 0; nf < 4; ++nf)
          acc[mf][nf] = MFMA_I8(af[mf], bfr[nf], acc[mf][nf]);
    }
    __syncthreads();
  }
  float sa = slot_scale(slots + slotA);
  int sbi = slotB0 + (qkvMode ? ((n0 >= 3072) ? 2 : (n0 >= 2048) ? 1 : 0) : 0);
  float ss = sa * slot_scale(slots + sbi);
  int rb = m0 + wr * 64, cb = n0 + wc * 64 + (lane & 15);
#pragma unroll
  for (int mf = 0; mf < 4; ++mf)
#pragma unroll
    for (int nf = 0; nf < 4; ++nf)
#pragma unroll
      for (int j = 0; j < 4; ++j) {
        size_t idx = (size_t)(rb + mf * 16 + (lane >> 4) * 4 + j) * N + cb + nf * 16;
        float val = (float)acc[mf][nf][j] * ss;
        if (outBf16) ((u16*)Cv)[idx] = f2bf(val);
        else ((float*)Cv)[idx] = val;
      }
}

// ---------- RoPE apply + per-head scatter (q and k); Y is bf16 ----------
// Q additionally scaled by C2 = log2e/sqrt(128) (folded out of attention).
__global__ void k_rope(const u16* __restrict__ Y, const float* __restrict__ ct,
                       const float* __restrict__ st_, u16* __restrict__ Qh,
                       u16* __restrict__ Kh) {
  int t = blockIdx.x * blockDim.x + threadIdx.x;
  const int QT = 4096 * 16 * 16;  // q-pairs/4
  bool isq = t < QT;
  int tt = isq ? t : t - QT;
  int d4 = tt & 15;
  int hh = isq ? ((tt >> 4) & 15) : ((tt >> 4) & 7);
  int row = isq ? (tt >> 8) : (tt >> 7);
  int s = row & 2047, bb = row >> 11;
  int d = d4 * 4;
  const u16* yp = Y + (size_t)row * 4096 + (isq ? hh * 128 : 2048 + hh * 128) + d;
  f32x4 a, bv;
#pragma unroll
  for (int j = 0; j < 4; ++j) { a[j] = bf2f(yp[j]); bv[j] = bf2f(yp[64 + j]); }
  f32x4 c = *(const f32x4*)(ct + s * 64 + d);
  f32x4 sn = *(const f32x4*)(st_ + s * 64 + d);
  f32x4 o0 = a * c - bv * sn;
  f32x4 o1 = bv * c + a * sn;
  if (isq) {
    const float C2 = 1.4426950408889634f * 0.08838834764831845f;
    o0 *= C2; o1 *= C2;
  }
  u16* dst = isq ? (Qh + ((size_t)(bb * 16 + hh) * 2048 + s) * 128 + d)
                 : (Kh + ((size_t)(bb * 8 + hh) * 2048 + s) * 128 + d);
  *(uint2*)dst = make_uint2(cvtpk(o0.x, o0.y), cvtpk(o0.z, o0.w));
  *(uint2*)(dst + 64) = make_uint2(cvtpk(o1.x, o1.y), cvtpk(o1.z, o1.w));
}

// ---------- V transpose (pure u16): Y v-cols -> Vth [b][hk][d=128][s=2048] ----------
__global__ void k_vtrans(const u16* __restrict__ Y, u16* __restrict__ Vth) {
  __shared__ u16 tile[64][72];
  int stile = blockIdx.x, dt = blockIdx.y, bh = blockIdx.z;
  int bb = bh >> 3, hk = bh & 7;
  int t = threadIdx.x;
#pragma unroll 4
  for (int i = 0; i < 16; ++i) {
    int e = i * 256 + t;
    int sl = e >> 6, dl = e & 63;
    tile[sl][dl] = Y[(size_t)(bb * 2048 + stile * 64 + sl) * 4096 + 3072 + hk * 128 +
                     dt * 64 + dl];
  }
  __syncthreads();
#pragma unroll 4
  for (int i = 0; i < 16; ++i) {
    int e = i * 256 + t;
    int dl = e >> 6, sl = e & 63;
    Vth[(size_t)((bb * 8 + hk) * 128 + dt * 64 + dl) * 2048 + stile * 64 + sl] = tile[sl][dl];
  }
}

// ---------- flash causal GQA attention (v6) ----------
// QBLK=64 (4 waves x 16 q-rows), KVBLK=64, single-buffered K/V LDS (41 KB ->
// 3 blocks/CU; TLP hides staging drains). Balanced pairing: block p does
// q-tiles {p, 31-p} => uniform 33 kv-iterations. Q pre-scaled by C2 in k_rope.
// cvt_pk packing. All waves active on every tile.
__global__ __launch_bounds__(256) void k_attn(
    const u16* __restrict__ Qh, const u16* __restrict__ Kh, const u16* __restrict__ Vth,
    float* __restrict__ attn, u32* __restrict__ amax_slot) {
  __shared__ __align__(16) u16 Ks[64 * 128];   // [kv][d], XOR-swizzled, 16 KB
  __shared__ __align__(16) u16 Vts[128 * 64];  // [d][kv], XOR-swizzled, 16 KB
  __shared__ __align__(16) u16 Pt[64 * 72];    // [q][kv] bf16, 144 B stride, 9 KB
  int p = blockIdx.x;                          // 0..15
  int h = blockIdx.y, b = blockIdx.z, hk = h >> 1;
  int tid = threadIdx.x, lane = tid & 63, w = tid >> 6;
  int q15 = lane & 15, g4 = lane >> 4;
  const u16* Qbase = Qh + ((size_t)(b * 16 + h) * 2048) * 128;
  const u16* Kbase = Kh + ((size_t)(b * 8 + hk) * 2048) * 128;
  const u16* Vbase = Vth + ((size_t)(b * 8 + hk) * 128) * 2048;
  float am = 0.f;

  auto stage_kv = [&](int kvb) {
#pragma unroll
    for (int c = 0; c < 4; ++c) {
      int chunk = w * 4 + c;
      int unit = chunk * 64 + lane;
      int rk = unit >> 4, pk = unit & 15, uk = pk ^ (rk & 7);
      gload16(Kbase + (size_t)(kvb + rk) * 128 + uk * 8, ((char*)Ks) + chunk * 1024);
      int rv = unit >> 3, pv = unit & 7, uv = pv ^ (rv & 7);
      gload16(Vbase + (size_t)rv * 2048 + kvb + uv * 8, ((char*)Vts) + chunk * 1024);
    }
  };

  for (int sub = 0; sub < 2; ++sub) {
    int qt = sub ? 31 - p : p;                 // 64-row q-tile index, 0..31
    int qrow0 = qt * 64 + w * 16;
    int qg = qrow0 + q15;
    bf16x8 qf[4];
#pragma unroll
    for (int ks = 0; ks < 4; ++ks)
      qf[ks] = *(const bf16x8*)(Qbase + (size_t)qg * 128 + ks * 32 + g4 * 8);
    f32x4 o[8] = {};
    float m0 = -1e30f, l0 = 0.f;
    int nkv = qt + 1;
    for (int t = 0; t < nkv; ++t) {
      int kvb = t * 64;
      stage_kv(kvb);
      __syncthreads();                         // tiles visible (implicit drain)
      // ---- S^T = K x Q^T (Q pre-scaled by C2) ----
      f32x4 s[4] = {};
#pragma unroll
      for (int ks = 0; ks < 4; ++ks)
#pragma unroll
        for (int f = 0; f < 4; ++f) {
          int rr = f * 16 + q15;
          int u = ks * 4 + g4;
          bf16x8 kf = *(const bf16x8*)((const char*)Ks + rr * 256 + ((u ^ (rr & 7)) << 4));
          s[f] = MFMA_BF16(kf, qf[ks], s[f]);
        }
      // ---- mask (diagonal tile only) + tile max ----
      bool needMask = (kvb + 63 > qrow0);
      float t0 = -1e30f;
#pragma unroll
      for (int f = 0; f < 4; ++f)
#pragma unroll
        for (int j = 0; j < 4; ++j) {
          float x0 = s[f][j];
          if (needMask) {
            int kvg = kvb + f * 16 + g4 * 4 + j;
            if (kvg > qg) x0 = -1e30f;
          }
          s[f][j] = x0;
          t0 = fmaxf(t0, x0);
        }
      t0 = fmaxf(t0, __shfl_xor(t0, 16));
      t0 = fmaxf(t0, __shfl_xor(t0, 32));
      // ---- defer-max ----
      if (!__all(t0 <= m0 + 8.f)) {
        float mn0 = fmaxf(m0, t0);
        float a0 = fexp2(m0 - mn0);
        m0 = mn0; l0 *= a0;
        float al[4];
#pragma unroll
        for (int j = 0; j < 4; ++j) al[j] = __shfl(a0, g4 * 4 + j);
#pragma unroll
        for (int nf = 0; nf < 8; ++nf)
#pragma unroll
          for (int j = 0; j < 4; ++j) o[nf][j] *= al[j];
      }
      // ---- P = exp2(s - m), row sum ----
      float ts0 = 0.f;
#pragma unroll
      for (int f = 0; f < 4; ++f)
#pragma unroll
        for (int j = 0; j < 4; ++j) {
          float p0 = fexp2(s[f][j] - m0);
          s[f][j] = p0;
          ts0 += p0;
        }
      ts0 += __shfl_xor(ts0, 16);
      ts0 += __shfl_xor(ts0, 32);
      l0 += ts0;
      // ---- pack P^T to LDS via cvt_pk (wave-private rows, no barrier) ----
#pragma unroll
      for (int f = 0; f < 4; ++f)
        *(uint2*)((char*)Pt + (w * 16 + q15) * 144 + (f * 16 + g4 * 4) * 2) =
            make_uint2(cvtpk(s[f][0], s[f][1]), cvtpk(s[f][2], s[f][3]));
      // ---- PV ----
#pragma unroll
      for (int ks2 = 0; ks2 < 2; ++ks2) {
        bf16x8 pf = *(const bf16x8*)((char*)Pt + (w * 16 + q15) * 144 +
                                     (ks2 * 32 + g4 * 8) * 2);
#pragma unroll
        for (int nf = 0; nf < 8; ++nf) {
          int rv = nf * 16 + q15;
          int u = ks2 * 4 + g4;
          bf16x8 vf = *(const bf16x8*)((const char*)Vts + rv * 128 + ((u ^ (rv & 7)) << 4));
          o[nf] = MFMA_BF16(pf, vf, o[nf]);
        }
      }
      __syncthreads();                         // all reads done before next stage
    }
    // ---- epilogue: normalize, store, absmax accumulate ----
    float i0 = 1.f / l0;
    float iv[4];
#pragma unroll
    for (int j = 0; j < 4; ++j) iv[j] = __shfl(i0, g4 * 4 + j);
    int colb = h * 128 + q15;
#pragma unroll
    for (int nf = 0; nf < 8; ++nf)
#pragma unroll
      for (int j = 0; j < 4; ++j) {
        int r0 = qrow0 + g4 * 4 + j;
        float v0 = o[nf][j] * iv[j];
        am = fmaxf(am, fabsf(v0));
        attn[(size_t)(b * 2048 + r0) * 2048 + colb + nf * 16] = v0;
      }
  }
#pragma unroll
  for (int d = 1; d < 64; d <<= 1) am = fmaxf(am, __shfl_xor(am, d));
  if (lane == 0) atomicMax(amax_slot, __float_as_uint(am));
}

// ---------- launch ----------
extern "C" void kernel_launch(void* const* d_in, const int* in_sizes, int n_in,
                              void* d_out, int out_size, void* d_ws, size_t ws_size,
                              hipStream_t stream) {
  const float* hs = (const float*)d_in[0];
  const float* wq = (const float*)d_in[1];
  const float* wk = (const float*)d_in[2];
  const float* wv = (const float*)d_in[3];
  const float* wo = (const float*)d_in[4];
  float* out = (float*)d_out;

  char* ws = (char*)d_ws;
  size_t off = 0;
  u32* scales = (u32*)ws; off += 256;                       // [x,wq,wk,wv,wo,attn]
  char* xq8 = ws + off;   off += (size_t)4096 * 2048;
  char* wqkv8 = ws + off; off += (size_t)4096 * 2048;       // rows: wq|wk|wv
  char* wo8 = ws + off;   off += (size_t)2048 * 2048;
  u16* Y = (u16*)(ws + off);       off += (size_t)4096 * 4096 * 2;   // bf16 now
  u16* Qh = (u16*)(ws + off);      off += (size_t)2 * 16 * 2048 * 128 * 2;
  u16* Kh = (u16*)(ws + off);      off += (size_t)2 * 8 * 2048 * 128 * 2;
  u16* Vth = (u16*)(ws + off);     off += (size_t)2 * 8 * 2048 * 128 * 2;
  float* attnb = (float*)(ws + off); off += (size_t)4096 * 2048 * 4;
  char* attn8 = ws + off;          off += (size_t)4096 * 2048;
  float* ctab = (float*)(ws + off); off += (size_t)2048 * 64 * 4;
  float* stab = (float*)(ws + off); off += (size_t)2048 * 64 * 4;

  hipMemsetAsync(scales, 0, 64, stream);

  hipLaunchKernelGGL(k_init, dim3(256, 1, 6), dim3(256), 0, stream,
                     hs, wq, wk, wv, wo, ctab, stab, scales);
  hipLaunchKernelGGL(k_quant5, dim3(512, 1, 5), dim3(256), 0, stream,
                     hs, wq, wk, wv, wo, xq8, wqkv8, wo8, scales);

  // QKV projection (exact int8): Y[4096][4096] bf16 = xq8 * wqkv8^T * scales
  hipLaunchKernelGGL(k_gemm_i8, dim3(32, 32), dim3(256), 0, stream,
                     xq8, wqkv8, (void*)Y, 4096, 4096, 2048, scales, 0, 1, 1, 1);

  hipLaunchKernelGGL(k_rope, dim3(6144), dim3(256), 0, stream, Y, ctab, stab, Qh, Kh);
  hipLaunchKernelGGL(k_vtrans, dim3(32, 2, 16), dim3(256), 0, stream, Y, Vth);

  hipLaunchKernelGGL(k_attn, dim3(16, 16, 2), dim3(256), 0, stream, Qh, Kh, Vth,
                     attnb, scales + 5);

  hipLaunchKernelGGL(k_quant_i8, dim3(8192), dim3(256), 0, stream, attnb, attn8,
                     2097152, scales + 5);

  // output projection (exact int8, f32 out) -> d_out
  hipLaunchKernelGGL(k_gemm_i8, dim3(16, 32), dim3(256), 0, stream,
                     attn8, wo8, (void*)out, 4096, 2048, 2048, scales, 5, 4, 0, 0);
}